// Round 7
// baseline (179.288 us; speedup 1.0000x reference)
//
#include <hip/hip_runtime.h>

#define B_    4
#define N_    2048
#define HID   512
#define NH    8
#define HD    64
#define TOK   (B_ * N_)   // 8192
#define LOG2E 1.4426950408889634f

typedef __attribute__((ext_vector_type(8))) short short8;
typedef __attribute__((ext_vector_type(4))) float f32x4;
typedef unsigned short u16;

// fp32 -> bf16 round-to-nearest-even
static __device__ __forceinline__ u16 f2bf(float f) {
    unsigned int u = __builtin_bit_cast(unsigned int, f);
    u += 0x7FFFu + ((u >> 16) & 1u);
    return (u16)(u >> 16);
}
static __device__ __forceinline__ float bf2f(u16 v) {
    return __builtin_bit_cast(float, (unsigned)v << 16);
}
// pack two fp32 -> bf16x2 by TRUNCATION: one v_perm_b32.
static __device__ __forceinline__ unsigned pktrunc(float a, float b) {
    return __builtin_amdgcn_perm(__builtin_bit_cast(unsigned, b),
                                 __builtin_bit_cast(unsigned, a), 0x07060302u);
}

// async global->LDS DMA, 16 B/lane. LDS dest = wave-uniform base + lane*16.
static __device__ __forceinline__ void dma16(const void* g, void* l) {
    __builtin_amdgcn_global_load_lds(
        (const __attribute__((address_space(1))) unsigned int*)(unsigned long long)g,
        (__attribute__((address_space(3))) unsigned int*)(unsigned int)(unsigned long long)l,
        16, 0, 0);
}

// ---------------------------------------------------------------------------
// One-launch fp32 -> bf16 convert for x + 4 weights.
// ---------------------------------------------------------------------------
__global__ __launch_bounds__(256) void cvt_all(
    const float* __restrict__ x,
    const float* __restrict__ w0, const float* __restrict__ w1,
    const float* __restrict__ w2, const float* __restrict__ w3,
    u16* __restrict__ xb,
    u16* __restrict__ d0, u16* __restrict__ d1,
    u16* __restrict__ d2, u16* __restrict__ d3)
{
    const int bid = blockIdx.x;
    const float* s;
    u16* d;
    int off;
    if (bid < 4096) { s = x; d = xb; off = bid; }
    else {
        const int t = (bid - 4096) >> 8;
        off = (bid - 4096) & 255;
        s = t == 0 ? w0 : t == 1 ? w1 : t == 2 ? w2 : w3;
        d = t == 0 ? d0 : t == 1 ? d1 : t == 2 ? d2 : d3;
    }
    const int i = off * 1024 + threadIdx.x * 4;
    const float4 v = *(const float4*)&s[i];
    ushort4 o;
    o.x = f2bf(v.x); o.y = f2bf(v.y); o.z = f2bf(v.z); o.w = f2bf(v.w);
    *(ushort4*)&d[i] = o;
}

// ---------------------------------------------------------------------------
// QKV GEMM (NT), DMA-staged dbuf, one barrier/K-step. 128x128 tile, BK=32.
// z<2 (Q/K): SWAPPED operands A=W (rows=head dims), B=x (rows=tokens) so the
// C-frag r-axis runs along head dims -> vectorized LDS-strip epilogue and
// coalesced b128 stores into (B,NH,N,HD). Q additionally (bias-added) scaled
// by log2e/8. z==2 (V): A=x, B=W; epilogue emits frag-packed V^T (B,NH,HD,N')
// with n' = 64*(n/64) + (n%16)*4 + (n%64)/16.
// ---------------------------------------------------------------------------
__global__ __launch_bounds__(256) void gemm_qkv(
    const u16* __restrict__ xb,
    const u16* __restrict__ W0, const u16* __restrict__ W1, const u16* __restrict__ W2,
    const float* __restrict__ bias0, const float* __restrict__ bias1, const float* __restrict__ bias2,
    u16* __restrict__ Qg, u16* __restrict__ Kg, u16* __restrict__ Vtg)
{
    const int z = blockIdx.z;
    const u16*   Wz   = z == 0 ? W0 : z == 1 ? W1 : W2;
    const float* bias = z == 0 ? bias0 : z == 1 ? bias1 : bias2;

    const u16* Ap; const u16* Bp; int arow0, brow0;
    if (z < 2) { Ap = Wz; Bp = xb; arow0 = blockIdx.y * 128; brow0 = blockIdx.x * 128; }
    else       { Ap = xb; Bp = Wz; arow0 = blockIdx.x * 128; brow0 = blockIdx.y * 128; }

    __shared__ u16 ABs[2][2][128 * 32];   // [buf][A/B][m*32 + c8'*8]

    const int tid  = threadIdx.x;
    const int w    = tid >> 6, lane = tid & 63;
    const int wr   = w >> 1, wc = w & 1;
    const int t16  = lane & 15, q4 = lane >> 4;

    const int dmr  = lane >> 2;
    const int dmc8 = (lane & 3) ^ ((lane >> 2) & 3) ^ ((lane >> 4) & 3);

    f32x4 acc[4][4];
    #pragma unroll
    for (int mt = 0; mt < 4; ++mt)
        #pragma unroll
        for (int nt = 0; nt < 4; ++nt)
            acc[mt][nt] = (f32x4){0.f, 0.f, 0.f, 0.f};

    #define QKV_DMA(p, k0)                                                      \
        _Pragma("unroll")                                                       \
        for (int i = 0; i < 2; ++i) {                                           \
            const int c = w * 2 + i;                                            \
            dma16(&Ap[(size_t)(arow0 + c * 16 + dmr) * HID + (k0) + dmc8 * 8],  \
                  &ABs[p][0][c * 512]);                                         \
            dma16(&Bp[(size_t)(brow0 + c * 16 + dmr) * HID + (k0) + dmc8 * 8],  \
                  &ABs[p][1][c * 512]);                                         \
        }

    QKV_DMA(0, 0)

    const int swz = (t16 ^ (t16 >> 2)) & 3;

    for (int it = 0; it < HID / 32; ++it) {
        __syncthreads();
        if (it + 1 < HID / 32) { QKV_DMA((it + 1) & 1, (it + 1) * 32) }

        const int p = it & 1;
        short8 af[4], bf[4];
        #pragma unroll
        for (int mt = 0; mt < 4; ++mt)
            af[mt] = *(const short8*)&ABs[p][0][(wr * 64 + mt * 16 + t16) * 32 + (q4 ^ swz) * 8];
        #pragma unroll
        for (int nt = 0; nt < 4; ++nt)
            bf[nt] = *(const short8*)&ABs[p][1][(wc * 64 + nt * 16 + t16) * 32 + (q4 ^ swz) * 8];
        #pragma unroll
        for (int mt = 0; mt < 4; ++mt)
            #pragma unroll
            for (int nt = 0; nt < 4; ++nt)
                acc[mt][nt] = __builtin_amdgcn_mfma_f32_16x16x32_bf16(
                    af[mt], bf[nt], acc[mt][nt], 0, 0, 0);
    }

    if (z < 2) {
        // Q/K epilogue: strip St[token np 0..128][dim jp 0..64] per half-pass.
        const float qs = (z == 0) ? 0.125f * LOG2E : 1.0f;
        u16* Cg = (z == 0) ? Qg : Kg;
        u16 (*St)[72] = (u16(*)[72])&ABs[0][0][0];   // 128 x 72 u16 = 18.4 KB
        #pragma unroll
        for (int p = 0; p < 2; ++p) {
            __syncthreads();
            if (wr == p) {
                #pragma unroll
                for (int mt = 0; mt < 4; ++mt) {
                    const f32x4 bv = *(const f32x4*)&bias[arow0 + p * 64 + mt * 16 + q4 * 4];
                    #pragma unroll
                    for (int nt = 0; nt < 4; ++nt) {
                        const int np = wc * 64 + nt * 16 + t16;
                        uint2 pk;
                        pk.x = pktrunc((acc[mt][nt][0] + bv[0]) * qs,
                                       (acc[mt][nt][1] + bv[1]) * qs);
                        pk.y = pktrunc((acc[mt][nt][2] + bv[2]) * qs,
                                       (acc[mt][nt][3] + bv[3]) * qs);
                        *(uint2*)&St[np][mt * 16 + q4 * 4] = pk;
                    }
                }
            }
            __syncthreads();
            const int h = blockIdx.y * 2 + p;
            #pragma unroll
            for (int it = 0; it < 4; ++it) {
                const int task = tid + it * 256;       // 0..1023
                const int np = task >> 3, ch = task & 7;
                const int nf = brow0 + np;
                const int b = nf >> 11, n = nf & (N_ - 1);
                *(short8*)&Cg[(((size_t)(b * NH + h)) * N_ + n) * HD + ch * 8] =
                    *(const short8*)&St[np][ch * 8];
            }
        }
    } else {
        // V epilogue: frag-packed V^T, coalesced b128 stores.
        u16 (*St)[72] = (u16(*)[72])&ABs[0][0][0];
        const int b = arow0 >> 11;
        #pragma unroll
        for (int p = 0; p < 2; ++p) {
            __syncthreads();
            if (wr == p) {
                #pragma unroll
                for (int nt = 0; nt < 4; ++nt) {
                    const int jp = wc * 64 + nt * 16 + t16;
                    const float bv = bias[brow0 + jp];
                    #pragma unroll
                    for (int mt = 0; mt < 4; ++mt) {
                        uint2 pk;
                        pk.x = pktrunc(acc[mt][nt][0] + bv, acc[mt][nt][1] + bv);
                        pk.y = pktrunc(acc[mt][nt][2] + bv, acc[mt][nt][3] + bv);
                        *(uint2*)&St[jp][mt * 16 + q4 * 4] = pk;
                    }
                }
            }
            __syncthreads();
            const int nb = (arow0 & (N_ - 1)) + p * 64;
            #pragma unroll
            for (int it = 0; it < 2; ++it) {
                const int task = tid + it * 256;
                const int jp = task >> 2, qc = task & 3;
                u16 v[16];
                #pragma unroll
                for (int e = 0; e < 16; ++e) {
                    const int np = qc * 16 + e;
                    const int n  = ((np & 3) << 4) | (np >> 2);
                    v[e] = St[jp][n];
                }
                const int j = brow0 + jp, h = j >> 6, d = j & 63;
                u16* dst = &Vtg[(((size_t)(b * NH + h)) * HD + d) * N_ + nb + qc * 16];
                *(short8*)(dst)     = *(const short8*)&v[0];
                *(short8*)(dst + 8) = *(const short8*)&v[8];
            }
        }
    }
}

// ---------------------------------------------------------------------------
// O-projection GEMM: 64x128 tiles -> grid (128,4) = 512 blocks (2/CU).
// A = AO bf16 (tokens), B = wo bf16, fp32 flat out.
// ---------------------------------------------------------------------------
__global__ __launch_bounds__(256) void gemm_o(
    const u16* __restrict__ A, const u16* __restrict__ W,
    const float* __restrict__ bias, float* __restrict__ C)
{
    __shared__ u16 ABs[2][(64 + 128) * 32];   // A strip 64x32 | B strip 128x32

    const int tid  = threadIdx.x;
    const int row0 = blockIdx.x * 64, col0 = blockIdx.y * 128;
    const int w    = tid >> 6, lane = tid & 63;
    const int wr   = w >> 1, wc = w & 1;
    const int t16  = lane & 15, q4 = lane >> 4;

    const int dmr  = lane >> 2;
    const int dmc8 = (lane & 3) ^ ((lane >> 2) & 3) ^ ((lane >> 4) & 3);

    f32x4 acc[2][4];
    #pragma unroll
    for (int mt = 0; mt < 2; ++mt)
        #pragma unroll
        for (int nt = 0; nt < 4; ++nt)
            acc[mt][nt] = (f32x4){0.f, 0.f, 0.f, 0.f};

    #define O_DMA(p, k0)                                                        \
        dma16(&A[(size_t)(row0 + w * 16 + dmr) * HID + (k0) + dmc8 * 8],        \
              &ABs[p][w * 512]);                                                \
        _Pragma("unroll")                                                       \
        for (int i = 0; i < 2; ++i) {                                           \
            const int c = w * 2 + i;                                            \
            dma16(&W[(size_t)(col0 + c * 16 + dmr) * HID + (k0) + dmc8 * 8],    \
                  &ABs[p][2048 + c * 512]);                                     \
        }

    O_DMA(0, 0)

    const int swz = (t16 ^ (t16 >> 2)) & 3;

    for (int it = 0; it < HID / 32; ++it) {
        __syncthreads();
        if (it + 1 < HID / 32) { O_DMA((it + 1) & 1, (it + 1) * 32) }

        const int p = it & 1;
        short8 af[2], bf[4];
        #pragma unroll
        for (int mt = 0; mt < 2; ++mt)
            af[mt] = *(const short8*)&ABs[p][(wr * 32 + mt * 16 + t16) * 32 + (q4 ^ swz) * 8];
        #pragma unroll
        for (int nt = 0; nt < 4; ++nt)
            bf[nt] = *(const short8*)&ABs[p][2048 + (wc * 64 + nt * 16 + t16) * 32 + (q4 ^ swz) * 8];
        #pragma unroll
        for (int mt = 0; mt < 2; ++mt)
            #pragma unroll
            for (int nt = 0; nt < 4; ++nt)
                acc[mt][nt] = __builtin_amdgcn_mfma_f32_16x16x32_bf16(
                    af[mt], bf[nt], acc[mt][nt], 0, 0, 0);
    }

    #pragma unroll
    for (int nt = 0; nt < 4; ++nt) {
        const int j = col0 + wc * 64 + nt * 16 + t16;
        const float bv = bias[j];
        #pragma unroll
        for (int mt = 0; mt < 2; ++mt)
            #pragma unroll
            for (int r = 0; r < 4; ++r) {
                const int i = row0 + wr * 32 + mt * 16 + q4 * 4 + r;
                C[(size_t)i * HID + j] = acc[mt][nt][r] + bv;
            }
    }
}

// ---------------------------------------------------------------------------
// MFMA flash attention, K-SPLIT x2 (blockIdx.z = key half). Fixed-max softmax,
// raw v_exp_f32, mask as bitwise AND on packed P, row-sum via ones-MFMA.
// Emits un-normalized partial O (bf16) + partial row-sum (fp32).
// Block = 256 threads (4 waves), 128 Q-rows, 16 K-tiles. LDS 53.2 KB -> 3/CU.
// ---------------------------------------------------------------------------
__global__ __launch_bounds__(256) void flash_mfma(
    const u16* __restrict__ Qg, const u16* __restrict__ Kg,
    const u16* __restrict__ Vtg, const unsigned char* __restrict__ msk,
    u16* __restrict__ Op, float* __restrict__ Lp)
{
    __shared__ u16 KVs[2][2][64 * 64];    // [buf][K/Vt][row*64 + c8'*8]
    __shared__ u16 Ps[4][32][72];         // per-wave P strip [row][c]
    __shared__ unsigned Mnd[16][32];      // AND-masks [kt][t16*2 + word]

    const int tid = threadIdx.x;
    const int w = tid >> 6, lane = tid & 63;
    const int t16 = lane & 15, q4 = lane >> 4;
    const int bh = blockIdx.y, b = bh >> 3;
    const int z = blockIdx.z;
    const int kofs = z * (N_ / 2);
    const int qrow0 = blockIdx.x * 128;
    const int qbase = qrow0 + w * 32;

    const size_t hb = (size_t)bh * N_ * HD;
    const u16* Qh  = Qg + hb;
    const u16* Kh  = Kg + hb;
    const u16* Vth = Vtg + hb;
    const unsigned char* mrow = msk + b * N_;

    // packed AND-mask table (16 kt x 32 slots)
    #pragma unroll
    for (int it = 0; it < 2; ++it) {
        const int e = tid + it * 256;          // 0..511
        const int kt = e >> 5, sl = e & 31;
        const int tt = sl >> 1, wd = sl & 1;
        const int k0 = kofs + kt * 64 + wd * 32 + tt;
        const unsigned lo = mrow[k0]      ? 0u : 0x0000FFFFu;
        const unsigned hi = mrow[k0 + 16] ? 0u : 0xFFFF0000u;
        Mnd[kt][sl] = lo | hi;
    }

    // Q fragments (A-layout: m = t16, k = q4*8 + j); Q pre-scaled by log2e/8
    short8 qf[2][2];
    #pragma unroll
    for (int mt = 0; mt < 2; ++mt)
        #pragma unroll
        for (int kk = 0; kk < 2; ++kk)
            qf[mt][kk] = *(const short8*)
                &Qh[(size_t)(qbase + mt * 16 + t16) * HD + kk * 32 + q4 * 8];

    const short8 ones8 = {0x3F80, 0x3F80, 0x3F80, 0x3F80,
                          0x3F80, 0x3F80, 0x3F80, 0x3F80};

    f32x4 o[2][4], ls[2];
    #pragma unroll
    for (int mt = 0; mt < 2; ++mt) {
        #pragma unroll
        for (int nt = 0; nt < 4; ++nt) o[mt][nt] = (f32x4){0.f, 0.f, 0.f, 0.f};
        ls[mt] = (f32x4){0.f, 0.f, 0.f, 0.f};
    }

    const int dmr  = lane >> 3;
    const int dmc8 = (lane & 7) ^ ((lane >> 3) & 7);

    #define FLASH_DMA(p, kb)                                                    \
        _Pragma("unroll")                                                       \
        for (int i = 0; i < 2; ++i) {                                           \
            const int c = w * 2 + i;                                            \
            dma16(&Kh[(size_t)((kb) + c * 8 + dmr) * HD + dmc8 * 8],            \
                  &KVs[p][0][c * 512]);                                         \
            dma16(&Vth[(size_t)(c * 8 + dmr) * N_ + (kb) + dmc8 * 8],           \
                  &KVs[p][1][c * 512]);                                         \
        }

    FLASH_DMA(0, kofs)

    const int swz7 = t16 & 7;

    for (int kt = 0; kt < 16; ++kt) {
        __syncthreads();
        if (kt + 1 < 16) { FLASH_DMA((kt + 1) & 1, kofs + (kt + 1) * 64) }
        const int p = kt & 1;

        // S = Q K^T (1/8 and log2e pre-folded into Q)
        f32x4 s[2][4];
        #pragma unroll
        for (int mt = 0; mt < 2; ++mt)
            #pragma unroll
            for (int f = 0; f < 4; ++f)
                s[mt][f] = (f32x4){0.f, 0.f, 0.f, 0.f};
        #pragma unroll
        for (int f = 0; f < 4; ++f) {
            #pragma unroll
            for (int kk = 0; kk < 2; ++kk) {
                const short8 kf = *(const short8*)
                    &KVs[p][0][(f * 16 + t16) * 64 + ((kk * 4 + q4) ^ swz7) * 8];
                #pragma unroll
                for (int mt = 0; mt < 2; ++mt)
                    s[mt][f] = __builtin_amdgcn_mfma_f32_16x16x32_bf16(
                        qf[mt][kk], kf, s[mt][f], 0, 0, 0);
            }
        }

        const uint2 mnd = *(const uint2*)&Mnd[kt][t16 * 2];

        // exp2 + truncation-pack + mask-AND + P store
        #pragma unroll
        for (int mt = 0; mt < 2; ++mt) {
            #pragma unroll
            for (int r = 0; r < 4; ++r) {
                const float e0 = __builtin_amdgcn_exp2f(s[mt][0][r]);
                const float e1 = __builtin_amdgcn_exp2f(s[mt][1][r]);
                const float e2 = __builtin_amdgcn_exp2f(s[mt][2][r]);
                const float e3 = __builtin_amdgcn_exp2f(s[mt][3][r]);
                uint2 pk;
                pk.x = pktrunc(e0, e1) & mnd.x;
                pk.y = pktrunc(e2, e3) & mnd.y;
                *(uint2*)&Ps[w][mt * 16 + q4 * 4 + r][t16 * 4] = pk;
            }
        }

        // O += P V ; row-sum += P * ones
        short8 pf[2][2];
        #pragma unroll
        for (int mt = 0; mt < 2; ++mt)
            #pragma unroll
            for (int kk = 0; kk < 2; ++kk)
                pf[mt][kk] = *(const short8*)&Ps[w][mt * 16 + t16][kk * 32 + q4 * 8];
        #pragma unroll
        for (int mt = 0; mt < 2; ++mt)
            #pragma unroll
            for (int kk = 0; kk < 2; ++kk)
                ls[mt] = __builtin_amdgcn_mfma_f32_16x16x32_bf16(
                    pf[mt][kk], ones8, ls[mt], 0, 0, 0);
        #pragma unroll
        for (int nt = 0; nt < 4; ++nt) {
            #pragma unroll
            for (int kk = 0; kk < 2; ++kk) {
                const short8 vf = *(const short8*)
                    &KVs[p][1][(nt * 16 + t16) * 64 + ((kk * 4 + q4) ^ swz7) * 8];
                #pragma unroll
                for (int mt = 0; mt < 2; ++mt)
                    o[mt][nt] = __builtin_amdgcn_mfma_f32_16x16x32_bf16(
                        pf[mt][kk], vf, o[mt][nt], 0, 0, 0);
            }
        }
    }

    // partial epilogue: un-normalized O (bf16) + row-sum (fp32, lane t16==0)
    const size_t obase = (((size_t)z * 32 + bh)) * N_ * HD;
    #pragma unroll
    for (int mt = 0; mt < 2; ++mt) {
        #pragma unroll
        for (int r = 0; r < 4; ++r) {
            const int n = qbase + mt * 16 + q4 * 4 + r;
            if (t16 == 0) Lp[((size_t)z * 32 + bh) * N_ + n] = ls[mt][r];
            #pragma unroll
            for (int nt = 0; nt < 4; ++nt)
                Op[obase + (size_t)n * HD + nt * 16 + t16] = f2bf(o[mt][nt][r]);
        }
    }
}

// ---------------------------------------------------------------------------
// Combine the two K-split halves: AO = (O0 + O1) / (l0 + l1), bf16 (B,N,HID).
// ---------------------------------------------------------------------------
__global__ __launch_bounds__(256) void reduce_o(
    const u16* __restrict__ Op, const float* __restrict__ Lp,
    u16* __restrict__ AOg)
{
    const int e = blockIdx.x * 256 + threadIdx.x;   // 0 .. 32*2048*16-1
    const int d4 = e & 15;
    const int n  = (e >> 4) & (N_ - 1);
    const int bh = e >> 15;
    const size_t base = (((size_t)bh) * N_ + n) * HD + d4 * 4;
    const ushort4 a = *(const ushort4*)&Op[base];
    const ushort4 c = *(const ushort4*)&Op[(size_t)32 * N_ * HD + base];
    const float inv = 1.f / (Lp[(size_t)bh * N_ + n] + Lp[(size_t)(32 + bh) * N_ + n]);
    ushort4 o;
    o.x = f2bf((bf2f(a.x) + bf2f(c.x)) * inv);
    o.y = f2bf((bf2f(a.y) + bf2f(c.y)) * inv);
    o.z = f2bf((bf2f(a.z) + bf2f(c.z)) * inv);
    o.w = f2bf((bf2f(a.w) + bf2f(c.w)) * inv);
    const int b = bh >> 3, h = bh & 7;
    *(ushort4*)&AOg[(((size_t)b * N_ + n)) * HID + h * 64 + d4 * 4] = o;
}

// ---------------------------------------------------------------------------
extern "C" void kernel_launch(void* const* d_in, const int* in_sizes, int n_in,
                              void* d_out, int out_size, void* d_ws, size_t ws_size,
                              hipStream_t stream) {
    const float* x  = (const float*)d_in[0];
    // d_in[1] = cancer_type (unused: bias_emb/keymod_emb cancel in softmax)
    const unsigned char* mask = (const unsigned char*)d_in[2];
    const float* wq = (const float*)d_in[3];
    const float* bq = (const float*)d_in[4];
    const float* wk = (const float*)d_in[5];
    const float* bk = (const float*)d_in[6];
    const float* wv = (const float*)d_in[7];
    const float* bv = (const float*)d_in[8];
    const float* wo = (const float*)d_in[9];
    const float* bo = (const float*)d_in[10];

    char* ws = (char*)d_ws;
    u16* xb  = (u16*)(ws);                      // 8 MB; reused as AOg after QKV
    u16* wqb = (u16*)(ws + (8u << 20));
    u16* wkb = (u16*)(ws + (8u << 20) + (512u << 10));
    u16* wvb = (u16*)(ws + (8u << 20) + (1024u << 10));
    u16* wob = (u16*)(ws + (8u << 20) + (1536u << 10));
    u16* Qg  = (u16*)(ws + (10u << 20));
    u16* Kg  = (u16*)(ws + (18u << 20));
    u16* Vtg = (u16*)(ws + (26u << 20));
    u16* Op  = (u16*)(ws + (34u << 20));        // 16 MB partial O (bf16)
    float* Lp = (float*)(ws + (50u << 20));     // 512 KB partial row-sums
    u16* AOg = xb;                              // alias: xb dead after QKV gemm

    cvt_all<<<5120, 256, 0, stream>>>(x, wq, wk, wv, wo, xb, wqb, wkb, wvb, wob);

    gemm_qkv<<<dim3(TOK / 128, HID / 128, 3), 256, 0, stream>>>(
        xb, wqb, wkb, wvb, bq, bk, bv, Qg, Kg, Vtg);

    flash_mfma<<<dim3(N_ / 128, B_ * NH, 2), 256, 0, stream>>>(
        Qg, Kg, Vtg, mask, Op, Lp);

    reduce_o<<<(32 * N_ * 16) / 256, 256, 0, stream>>>(Op, Lp, AOg);

    gemm_o<<<dim3(TOK / 64, HID / 128), 256, 0, stream>>>(
        AOg, wob, bo, (float*)d_out);
}

// Round 8
// 178.812 us; speedup vs baseline: 1.0027x; 1.0027x over previous
//
#include <hip/hip_runtime.h>

#define B_    4
#define N_    2048
#define HID   512
#define NH    8
#define HD    64
#define TOK   (B_ * N_)   // 8192
#define LOG2E 1.4426950408889634f

typedef __attribute__((ext_vector_type(8))) short short8;
typedef __attribute__((ext_vector_type(4))) float f32x4;
typedef unsigned short u16;

// fp32 -> bf16 round-to-nearest-even
static __device__ __forceinline__ u16 f2bf(float f) {
    unsigned int u = __builtin_bit_cast(unsigned int, f);
    u += 0x7FFFu + ((u >> 16) & 1u);
    return (u16)(u >> 16);
}
static __device__ __forceinline__ float bf2f(u16 v) {
    return __builtin_bit_cast(float, (unsigned)v << 16);
}
// pack two fp32 -> bf16x2 by TRUNCATION: one v_perm_b32.
static __device__ __forceinline__ unsigned pktrunc(float a, float b) {
    return __builtin_amdgcn_perm(__builtin_bit_cast(unsigned, b),
                                 __builtin_bit_cast(unsigned, a), 0x07060302u);
}

// async global->LDS DMA, 16 B/lane. LDS dest = wave-uniform base + lane*16.
static __device__ __forceinline__ void dma16(const void* g, void* l) {
    __builtin_amdgcn_global_load_lds(
        (const __attribute__((address_space(1))) unsigned int*)(unsigned long long)g,
        (__attribute__((address_space(3))) unsigned int*)(unsigned int)(unsigned long long)l,
        16, 0, 0);
}

// ---------------------------------------------------------------------------
// One-launch fp32 -> bf16 convert for x + 4 weights.
// ---------------------------------------------------------------------------
__global__ __launch_bounds__(256) void cvt_all(
    const float* __restrict__ x,
    const float* __restrict__ w0, const float* __restrict__ w1,
    const float* __restrict__ w2, const float* __restrict__ w3,
    u16* __restrict__ xb,
    u16* __restrict__ d0, u16* __restrict__ d1,
    u16* __restrict__ d2, u16* __restrict__ d3)
{
    const int bid = blockIdx.x;
    const float* s;
    u16* d;
    int off;
    if (bid < 4096) { s = x; d = xb; off = bid; }
    else {
        const int t = (bid - 4096) >> 8;
        off = (bid - 4096) & 255;
        s = t == 0 ? w0 : t == 1 ? w1 : t == 2 ? w2 : w3;
        d = t == 0 ? d0 : t == 1 ? d1 : t == 2 ? d2 : d3;
    }
    const int i = off * 1024 + threadIdx.x * 4;
    const float4 v = *(const float4*)&s[i];
    ushort4 o;
    o.x = f2bf(v.x); o.y = f2bf(v.y); o.z = f2bf(v.z); o.w = f2bf(v.w);
    *(ushort4*)&d[i] = o;
}

// ---------------------------------------------------------------------------
// QKV GEMM (NT), DMA-staged dbuf, one barrier/K-step, K-loop UNROLLED x2 so
// LDS buffer indices are compile-time. 128x128 tile, BK=32.
// z<2 (Q/K): A=W (rows=head dims), B=x (rows=tokens); coalesced b128 stores
// into (B,NH,N,HD); Q scaled by log2e/8. z==2 (V): A=x, B=W; frag-packed V^T.
// ---------------------------------------------------------------------------
__global__ __launch_bounds__(256) void gemm_qkv(
    const u16* __restrict__ xb,
    const u16* __restrict__ W0, const u16* __restrict__ W1, const u16* __restrict__ W2,
    const float* __restrict__ bias0, const float* __restrict__ bias1, const float* __restrict__ bias2,
    u16* __restrict__ Qg, u16* __restrict__ Kg, u16* __restrict__ Vtg)
{
    const int z = blockIdx.z;
    const u16*   Wz   = z == 0 ? W0 : z == 1 ? W1 : W2;
    const float* bias = z == 0 ? bias0 : z == 1 ? bias1 : bias2;

    const u16* Ap; const u16* Bp; int arow0, brow0;
    if (z < 2) { Ap = Wz; Bp = xb; arow0 = blockIdx.y * 128; brow0 = blockIdx.x * 128; }
    else       { Ap = xb; Bp = Wz; arow0 = blockIdx.x * 128; brow0 = blockIdx.y * 128; }

    __shared__ u16 ABs[2][2][128 * 32];   // [buf][A/B][m*32 + c8'*8]

    const int tid  = threadIdx.x;
    const int w    = tid >> 6, lane = tid & 63;
    const int wr   = w >> 1, wc = w & 1;
    const int t16  = lane & 15, q4 = lane >> 4;

    const int dmr  = lane >> 2;
    const int dmc8 = (lane & 3) ^ ((lane >> 2) & 3) ^ ((lane >> 4) & 3);

    f32x4 acc[4][4];
    #pragma unroll
    for (int mt = 0; mt < 4; ++mt)
        #pragma unroll
        for (int nt = 0; nt < 4; ++nt)
            acc[mt][nt] = (f32x4){0.f, 0.f, 0.f, 0.f};

    #define QKV_DMA(p, k0)                                                      \
        _Pragma("unroll")                                                       \
        for (int i = 0; i < 2; ++i) {                                           \
            const int c = w * 2 + i;                                            \
            dma16(&Ap[(size_t)(arow0 + c * 16 + dmr) * HID + (k0) + dmc8 * 8],  \
                  &ABs[p][0][c * 512]);                                         \
            dma16(&Bp[(size_t)(brow0 + c * 16 + dmr) * HID + (k0) + dmc8 * 8],  \
                  &ABs[p][1][c * 512]);                                         \
        }

    const int swz = (t16 ^ (t16 >> 2)) & 3;

    auto qstep = [&](const int p) {
        short8 af[4], bf[4];
        #pragma unroll
        for (int mt = 0; mt < 4; ++mt)
            af[mt] = *(const short8*)&ABs[p][0][(wr * 64 + mt * 16 + t16) * 32 + (q4 ^ swz) * 8];
        #pragma unroll
        for (int nt = 0; nt < 4; ++nt)
            bf[nt] = *(const short8*)&ABs[p][1][(wc * 64 + nt * 16 + t16) * 32 + (q4 ^ swz) * 8];
        #pragma unroll
        for (int mt = 0; mt < 4; ++mt)
            #pragma unroll
            for (int nt = 0; nt < 4; ++nt)
                acc[mt][nt] = __builtin_amdgcn_mfma_f32_16x16x32_bf16(
                    af[mt], bf[nt], acc[mt][nt], 0, 0, 0);
    };

    QKV_DMA(0, 0)
    for (int it = 0; it < 16; it += 2) {
        __syncthreads();
        QKV_DMA(1, (it + 1) * 32)
        qstep(0);
        __syncthreads();
        if (it + 2 < 16) { QKV_DMA(0, (it + 2) * 32) }
        qstep(1);
    }

    if (z < 2) {
        // Q/K epilogue: strip St[token np][dim] per half-pass; coalesced stores.
        const float qs = (z == 0) ? 0.125f * LOG2E : 1.0f;
        u16* Cg = (z == 0) ? Qg : Kg;
        u16 (*St)[72] = (u16(*)[72])&ABs[0][0][0];
        #pragma unroll
        for (int p = 0; p < 2; ++p) {
            __syncthreads();
            if (wr == p) {
                #pragma unroll
                for (int mt = 0; mt < 4; ++mt) {
                    const f32x4 bv = *(const f32x4*)&bias[arow0 + p * 64 + mt * 16 + q4 * 4];
                    #pragma unroll
                    for (int nt = 0; nt < 4; ++nt) {
                        const int np = wc * 64 + nt * 16 + t16;
                        uint2 pk;
                        pk.x = pktrunc((acc[mt][nt][0] + bv[0]) * qs,
                                       (acc[mt][nt][1] + bv[1]) * qs);
                        pk.y = pktrunc((acc[mt][nt][2] + bv[2]) * qs,
                                       (acc[mt][nt][3] + bv[3]) * qs);
                        *(uint2*)&St[np][mt * 16 + q4 * 4] = pk;
                    }
                }
            }
            __syncthreads();
            const int h = blockIdx.y * 2 + p;
            #pragma unroll
            for (int it = 0; it < 4; ++it) {
                const int task = tid + it * 256;
                const int np = task >> 3, ch = task & 7;
                const int nf = brow0 + np;
                const int b = nf >> 11, n = nf & (N_ - 1);
                *(short8*)&Cg[(((size_t)(b * NH + h)) * N_ + n) * HD + ch * 8] =
                    *(const short8*)&St[np][ch * 8];
            }
        }
    } else {
        // V epilogue: frag-packed V^T (n' = 64*(n/64) + (n%16)*4 + (n%64)/16).
        u16 (*St)[72] = (u16(*)[72])&ABs[0][0][0];
        const int b = arow0 >> 11;
        #pragma unroll
        for (int p = 0; p < 2; ++p) {
            __syncthreads();
            if (wr == p) {
                #pragma unroll
                for (int nt = 0; nt < 4; ++nt) {
                    const int jp = wc * 64 + nt * 16 + t16;
                    const float bv = bias[brow0 + jp];
                    #pragma unroll
                    for (int mt = 0; mt < 4; ++mt) {
                        uint2 pk;
                        pk.x = pktrunc(acc[mt][nt][0] + bv, acc[mt][nt][1] + bv);
                        pk.y = pktrunc(acc[mt][nt][2] + bv, acc[mt][nt][3] + bv);
                        *(uint2*)&St[jp][mt * 16 + q4 * 4] = pk;
                    }
                }
            }
            __syncthreads();
            const int nb = (arow0 & (N_ - 1)) + p * 64;
            #pragma unroll
            for (int it = 0; it < 2; ++it) {
                const int task = tid + it * 256;
                const int jp = task >> 2, qc = task & 3;
                u16 v[16];
                #pragma unroll
                for (int e = 0; e < 16; ++e) {
                    const int np = qc * 16 + e;
                    const int n  = ((np & 3) << 4) | (np >> 2);
                    v[e] = St[jp][n];
                }
                const int j = brow0 + jp, h = j >> 6, d = j & 63;
                u16* dst = &Vtg[(((size_t)(b * NH + h)) * HD + d) * N_ + nb + qc * 16];
                *(short8*)(dst)     = *(const short8*)&v[0];
                *(short8*)(dst + 8) = *(const short8*)&v[8];
            }
        }
    }
}

// ---------------------------------------------------------------------------
// MFMA flash attention, K-SPLIT x2 (blockIdx.z), UNROLLED x2 K-loop. Fixed-max
// softmax, raw v_exp_f32, mask as bitwise AND on packed P, row-sum via
// ones-MFMA. Emits un-normalized partial O (bf16) + partial row-sum (fp32).
// ---------------------------------------------------------------------------
__global__ __launch_bounds__(256) void flash_mfma(
    const u16* __restrict__ Qg, const u16* __restrict__ Kg,
    const u16* __restrict__ Vtg, const unsigned char* __restrict__ msk,
    u16* __restrict__ Op, float* __restrict__ Lp)
{
    __shared__ u16 KVs[2][2][64 * 64];    // [buf][K/Vt][row*64 + c8'*8]
    __shared__ u16 Ps[4][32][72];         // per-wave P strip [row][c]
    __shared__ unsigned Mnd[16][32];      // AND-masks [kt][t16*2 + word]

    const int tid = threadIdx.x;
    const int w = tid >> 6, lane = tid & 63;
    const int t16 = lane & 15, q4 = lane >> 4;
    const int bh = blockIdx.y, b = bh >> 3;
    const int z = blockIdx.z;
    const int kofs = z * (N_ / 2);
    const int qrow0 = blockIdx.x * 128;
    const int qbase = qrow0 + w * 32;

    const size_t hb = (size_t)bh * N_ * HD;
    const u16* Qh  = Qg + hb;
    const u16* Kh  = Kg + hb;
    const u16* Vth = Vtg + hb;
    const unsigned char* mrow = msk + b * N_;

    #pragma unroll
    for (int it = 0; it < 2; ++it) {
        const int e = tid + it * 256;
        const int kt = e >> 5, sl = e & 31;
        const int tt = sl >> 1, wd = sl & 1;
        const int k0 = kofs + kt * 64 + wd * 32 + tt;
        const unsigned lo = mrow[k0]      ? 0u : 0x0000FFFFu;
        const unsigned hi = mrow[k0 + 16] ? 0u : 0xFFFF0000u;
        Mnd[kt][sl] = lo | hi;
    }

    short8 qf[2][2];
    #pragma unroll
    for (int mt = 0; mt < 2; ++mt)
        #pragma unroll
        for (int kk = 0; kk < 2; ++kk)
            qf[mt][kk] = *(const short8*)
                &Qh[(size_t)(qbase + mt * 16 + t16) * HD + kk * 32 + q4 * 8];

    const short8 ones8 = {0x3F80, 0x3F80, 0x3F80, 0x3F80,
                          0x3F80, 0x3F80, 0x3F80, 0x3F80};

    f32x4 o[2][4], ls[2];
    #pragma unroll
    for (int mt = 0; mt < 2; ++mt) {
        #pragma unroll
        for (int nt = 0; nt < 4; ++nt) o[mt][nt] = (f32x4){0.f, 0.f, 0.f, 0.f};
        ls[mt] = (f32x4){0.f, 0.f, 0.f, 0.f};
    }

    const int dmr  = lane >> 3;
    const int dmc8 = (lane & 7) ^ ((lane >> 3) & 7);

    #define FLASH_DMA(p, kb)                                                    \
        _Pragma("unroll")                                                       \
        for (int i = 0; i < 2; ++i) {                                           \
            const int c = w * 2 + i;                                            \
            dma16(&Kh[(size_t)((kb) + c * 8 + dmr) * HD + dmc8 * 8],            \
                  &KVs[p][0][c * 512]);                                         \
            dma16(&Vth[(size_t)(c * 8 + dmr) * N_ + (kb) + dmc8 * 8],           \
                  &KVs[p][1][c * 512]);                                         \
        }

    const int swz7 = t16 & 7;

    auto fstep = [&](const int p, const int kt) {
        // S = Q K^T (1/8 and log2e pre-folded into Q)
        f32x4 s[2][4];
        #pragma unroll
        for (int mt = 0; mt < 2; ++mt)
            #pragma unroll
            for (int f = 0; f < 4; ++f)
                s[mt][f] = (f32x4){0.f, 0.f, 0.f, 0.f};
        #pragma unroll
        for (int f = 0; f < 4; ++f) {
            #pragma unroll
            for (int kk = 0; kk < 2; ++kk) {
                const short8 kf = *(const short8*)
                    &KVs[p][0][(f * 16 + t16) * 64 + ((kk * 4 + q4) ^ swz7) * 8];
                #pragma unroll
                for (int mt = 0; mt < 2; ++mt)
                    s[mt][f] = __builtin_amdgcn_mfma_f32_16x16x32_bf16(
                        qf[mt][kk], kf, s[mt][f], 0, 0, 0);
            }
        }

        const uint2 mnd = *(const uint2*)&Mnd[kt][t16 * 2];

        // exp2 + truncation-pack + mask-AND + P store
        #pragma unroll
        for (int mt = 0; mt < 2; ++mt) {
            #pragma unroll
            for (int r = 0; r < 4; ++r) {
                const float e0 = __builtin_amdgcn_exp2f(s[mt][0][r]);
                const float e1 = __builtin_amdgcn_exp2f(s[mt][1][r]);
                const float e2 = __builtin_amdgcn_exp2f(s[mt][2][r]);
                const float e3 = __builtin_amdgcn_exp2f(s[mt][3][r]);
                uint2 pk;
                pk.x = pktrunc(e0, e1) & mnd.x;
                pk.y = pktrunc(e2, e3) & mnd.y;
                *(uint2*)&Ps[w][mt * 16 + q4 * 4 + r][t16 * 4] = pk;
            }
        }

        // O += P V ; row-sum += P * ones
        short8 pf[2][2];
        #pragma unroll
        for (int mt = 0; mt < 2; ++mt)
            #pragma unroll
            for (int kk = 0; kk < 2; ++kk)
                pf[mt][kk] = *(const short8*)&Ps[w][mt * 16 + t16][kk * 32 + q4 * 8];
        #pragma unroll
        for (int mt = 0; mt < 2; ++mt)
            #pragma unroll
            for (int kk = 0; kk < 2; ++kk)
                ls[mt] = __builtin_amdgcn_mfma_f32_16x16x32_bf16(
                    pf[mt][kk], ones8, ls[mt], 0, 0, 0);
        #pragma unroll
        for (int nt = 0; nt < 4; ++nt) {
            #pragma unroll
            for (int kk = 0; kk < 2; ++kk) {
                const short8 vf = *(const short8*)
                    &KVs[p][1][(nt * 16 + t16) * 64 + ((kk * 4 + q4) ^ swz7) * 8];
                #pragma unroll
                for (int mt = 0; mt < 2; ++mt)
                    o[mt][nt] = __builtin_amdgcn_mfma_f32_16x16x32_bf16(
                        pf[mt][kk], vf, o[mt][nt], 0, 0, 0);
            }
        }
    };

    FLASH_DMA(0, kofs)
    for (int kt = 0; kt < 16; kt += 2) {
        __syncthreads();
        FLASH_DMA(1, kofs + (kt + 1) * 64)
        fstep(0, kt);
        __syncthreads();
        if (kt + 2 < 16) { FLASH_DMA(0, kofs + (kt + 2) * 64) }
        fstep(1, kt + 1);
    }

    // partial epilogue: un-normalized O (bf16) + row-sum (fp32, lane t16==0)
    const size_t obase = (((size_t)z * 32 + bh)) * N_ * HD;
    #pragma unroll
    for (int mt = 0; mt < 2; ++mt) {
        #pragma unroll
        for (int r = 0; r < 4; ++r) {
            const int n = qbase + mt * 16 + q4 * 4 + r;
            if (t16 == 0) Lp[((size_t)z * 32 + bh) * N_ + n] = ls[mt][r];
            #pragma unroll
            for (int nt = 0; nt < 4; ++nt)
                Op[obase + (size_t)n * HD + nt * 16 + t16] = f2bf(o[mt][nt][r]);
        }
    }
}

// ---------------------------------------------------------------------------
// O-projection GEMM with FUSED K-split combine + per-head normalization.
// C[i][j] = sum_{h,d} ((O0+O1)[b,h,n,d] / (l0+l1)[b,h,n]) * wo[j][h*64+d] + bo[j]
// Tile 32x128, grid (256,4) = 1024 blocks (4/CU). A-side VALU-staged (combine+
// normalize, bf16-pack); B-side (wo) DMA dbuf. One barrier per K-step.
// ---------------------------------------------------------------------------
__global__ __launch_bounds__(256) void gemm_o2(
    const u16* __restrict__ Op, const float* __restrict__ Lp,
    const u16* __restrict__ W, const float* __restrict__ bias,
    float* __restrict__ C)
{
    __shared__ u16 As[2][32][40];         // padded, VALU-staged
    __shared__ u16 Bs[2][128 * 32];       // DMA, XOR-swizzled

    const int tid  = threadIdx.x;
    const int row0 = blockIdx.x * 32, col0 = blockIdx.y * 128;
    const int w    = tid >> 6, lane = tid & 63;
    const int wr   = w >> 1, wc = w & 1;
    const int t16  = lane & 15, q4 = lane >> 4;

    const int dmr  = lane >> 2;
    const int dmc8 = (lane & 3) ^ ((lane >> 2) & 3) ^ ((lane >> 4) & 3);

    f32x4 acc[4];
    #pragma unroll
    for (int nt = 0; nt < 4; ++nt) acc[nt] = (f32x4){0.f, 0.f, 0.f, 0.f};

    #define O2_DMA(p, k0)                                                       \
        _Pragma("unroll")                                                       \
        for (int i = 0; i < 2; ++i) {                                           \
            const int c = w * 2 + i;                                            \
            dma16(&W[(size_t)(col0 + c * 16 + dmr) * HID + (k0) + dmc8 * 8],    \
                  &Bs[p][c * 512]);                                             \
        }

    // A prefetch state (threads 0..127): chunk = 8 dims of one token row
    const int tr = tid >> 2, dcol = (tid & 3) * 8;
    const int itok = row0 + tr;
    const int ab = itok >> 11, an = itok & (N_ - 1);
    short8 a0, a1;
    float inv;
    const size_t OP_HALF = (size_t)32 * N_ * HD;

    auto aload = [&](const int t) {
        const int h = t >> 1, dk = (t & 1) * 32;
        const size_t li  = ((size_t)(ab * NH + h)) * N_ + an;
        const size_t off = li * HD + dk + dcol;
        a0 = *(const short8*)&Op[off];
        a1 = *(const short8*)&Op[off + OP_HALF];
        inv = 1.f / (Lp[li] + Lp[li + (size_t)32 * N_]);
    };

    const int swz = (t16 ^ (t16 >> 2)) & 3;

    auto ostep = [&](const int p, const int t) {
        // stage A(t): combine halves, normalize, pack
        if (tid < 128) {
            float v[8];
            #pragma unroll
            for (int i = 0; i < 8; ++i)
                v[i] = (bf2f((u16)a0[i]) + bf2f((u16)a1[i])) * inv;
            uint4 pk;
            pk.x = pktrunc(v[0], v[1]);
            pk.y = pktrunc(v[2], v[3]);
            pk.z = pktrunc(v[4], v[5]);
            pk.w = pktrunc(v[6], v[7]);
            *(uint4*)&As[p][tr][dcol] = pk;
        }
        __syncthreads();             // A(t) visible; drains B-DMA(t)
        if (t + 1 < 16) {
            O2_DMA(p ^ 1, (t + 1) * 32)
            if (tid < 128) aload(t + 1);
        }
        // compute(t)
        const short8 af = *(const short8*)&As[p][wr * 16 + t16][q4 * 8];
        short8 bf[4];
        #pragma unroll
        for (int nt = 0; nt < 4; ++nt)
            bf[nt] = *(const short8*)&Bs[p][(wc * 64 + nt * 16 + t16) * 32 + (q4 ^ swz) * 8];
        #pragma unroll
        for (int nt = 0; nt < 4; ++nt)
            acc[nt] = __builtin_amdgcn_mfma_f32_16x16x32_bf16(af, bf[nt], acc[nt], 0, 0, 0);
    };

    O2_DMA(0, 0)
    if (tid < 128) aload(0);
    for (int t = 0; t < 16; t += 2) {
        ostep(0, t);
        ostep(1, t + 1);
    }

    // epilogue: fp32 out + bias (normalization already applied on A)
    #pragma unroll
    for (int nt = 0; nt < 4; ++nt) {
        const int j = col0 + wc * 64 + nt * 16 + t16;
        const float bv = bias[j];
        #pragma unroll
        for (int r = 0; r < 4; ++r) {
            const int i = row0 + wr * 16 + q4 * 4 + r;
            C[(size_t)i * HID + j] = acc[nt][r] + bv;
        }
    }
}

// ---------------------------------------------------------------------------
extern "C" void kernel_launch(void* const* d_in, const int* in_sizes, int n_in,
                              void* d_out, int out_size, void* d_ws, size_t ws_size,
                              hipStream_t stream) {
    const float* x  = (const float*)d_in[0];
    // d_in[1] = cancer_type (unused: bias_emb/keymod_emb cancel in softmax)
    const unsigned char* mask = (const unsigned char*)d_in[2];
    const float* wq = (const float*)d_in[3];
    const float* bq = (const float*)d_in[4];
    const float* wk = (const float*)d_in[5];
    const float* bk = (const float*)d_in[6];
    const float* wv = (const float*)d_in[7];
    const float* bv = (const float*)d_in[8];
    const float* wo = (const float*)d_in[9];
    const float* bo = (const float*)d_in[10];

    char* ws = (char*)d_ws;
    u16* xb  = (u16*)(ws);
    u16* wqb = (u16*)(ws + (8u << 20));
    u16* wkb = (u16*)(ws + (8u << 20) + (512u << 10));
    u16* wvb = (u16*)(ws + (8u << 20) + (1024u << 10));
    u16* wob = (u16*)(ws + (8u << 20) + (1536u << 10));
    u16* Qg  = (u16*)(ws + (10u << 20));
    u16* Kg  = (u16*)(ws + (18u << 20));
    u16* Vtg = (u16*)(ws + (26u << 20));
    u16* Op  = (u16*)(ws + (34u << 20));        // 16 MB partial O (bf16)
    float* Lp = (float*)(ws + (50u << 20));     // 512 KB partial row-sums

    cvt_all<<<5120, 256, 0, stream>>>(x, wq, wk, wv, wo, xb, wqb, wkb, wvb, wob);

    gemm_qkv<<<dim3(TOK / 128, HID / 128, 3), 256, 0, stream>>>(
        xb, wqb, wkb, wvb, bq, bk, bv, Qg, Kg, Vtg);

    flash_mfma<<<dim3(N_ / 128, B_ * NH, 2), 256, 0, stream>>>(
        Qg, Kg, Vtg, mask, Op, Lp);

    gemm_o2<<<dim3(TOK / 32, HID / 128), 256, 0, stream>>>(
        Op, Lp, wob, bo, (float*)d_out);
}

// Round 9
// 169.542 us; speedup vs baseline: 1.0575x; 1.0547x over previous
//
#include <hip/hip_runtime.h>

#define B_    4
#define N_    2048
#define HID   512
#define NH    8
#define HD    64
#define TOK   (B_ * N_)   // 8192
#define LOG2E 1.4426950408889634f

typedef __attribute__((ext_vector_type(8))) short short8;
typedef __attribute__((ext_vector_type(4))) float f32x4;
typedef unsigned short u16;

// fp32 -> bf16 round-to-nearest-even
static __device__ __forceinline__ u16 f2bf(float f) {
    unsigned int u = __builtin_bit_cast(unsigned int, f);
    u += 0x7FFFu + ((u >> 16) & 1u);
    return (u16)(u >> 16);
}
static __device__ __forceinline__ float bf2f(u16 v) {
    return __builtin_bit_cast(float, (unsigned)v << 16);
}
// pack two fp32 -> bf16x2 by TRUNCATION: one v_perm_b32.
static __device__ __forceinline__ unsigned pktrunc(float a, float b) {
    return __builtin_amdgcn_perm(__builtin_bit_cast(unsigned, b),
                                 __builtin_bit_cast(unsigned, a), 0x07060302u);
}

// async global->LDS DMA, 16 B/lane. LDS dest = wave-uniform base + lane*16.
static __device__ __forceinline__ void dma16(const void* g, void* l) {
    __builtin_amdgcn_global_load_lds(
        (const __attribute__((address_space(1))) unsigned int*)(unsigned long long)g,
        (__attribute__((address_space(3))) unsigned int*)(unsigned int)(unsigned long long)l,
        16, 0, 0);
}

// ---------------------------------------------------------------------------
// One-launch fp32 -> bf16 convert for x + 4 weights.
// ---------------------------------------------------------------------------
__global__ __launch_bounds__(256) void cvt_all(
    const float* __restrict__ x,
    const float* __restrict__ w0, const float* __restrict__ w1,
    const float* __restrict__ w2, const float* __restrict__ w3,
    u16* __restrict__ xb,
    u16* __restrict__ d0, u16* __restrict__ d1,
    u16* __restrict__ d2, u16* __restrict__ d3)
{
    const int bid = blockIdx.x;
    const float* s;
    u16* d;
    int off;
    if (bid < 4096) { s = x; d = xb; off = bid; }
    else {
        const int t = (bid - 4096) >> 8;
        off = (bid - 4096) & 255;
        s = t == 0 ? w0 : t == 1 ? w1 : t == 2 ? w2 : w3;
        d = t == 0 ? d0 : t == 1 ? d1 : t == 2 ? d2 : d3;
    }
    const int i = off * 1024 + threadIdx.x * 4;
    const float4 v = *(const float4*)&s[i];
    ushort4 o;
    o.x = f2bf(v.x); o.y = f2bf(v.y); o.z = f2bf(v.z); o.w = f2bf(v.w);
    *(ushort4*)&d[i] = o;
}

// ---------------------------------------------------------------------------
// QKV GEMM (NT), DMA-staged dbuf, one barrier/K-step, K-loop UNROLLED x2.
// 128x128 tile, BK=32. z<2 (Q/K): A=W (rows=head dims), B=x (rows=tokens);
// coalesced b128 stores into (B,NH,N,HD); Q scaled by log2e/8.
// z==2 (V): A=x, B=W; frag-packed V^T (B,NH,HD,N').
// ---------------------------------------------------------------------------
__global__ __launch_bounds__(256) void gemm_qkv(
    const u16* __restrict__ xb,
    const u16* __restrict__ W0, const u16* __restrict__ W1, const u16* __restrict__ W2,
    const float* __restrict__ bias0, const float* __restrict__ bias1, const float* __restrict__ bias2,
    u16* __restrict__ Qg, u16* __restrict__ Kg, u16* __restrict__ Vtg)
{
    const int z = blockIdx.z;
    const u16*   Wz   = z == 0 ? W0 : z == 1 ? W1 : W2;
    const float* bias = z == 0 ? bias0 : z == 1 ? bias1 : bias2;

    const u16* Ap; const u16* Bp; int arow0, brow0;
    if (z < 2) { Ap = Wz; Bp = xb; arow0 = blockIdx.y * 128; brow0 = blockIdx.x * 128; }
    else       { Ap = xb; Bp = Wz; arow0 = blockIdx.x * 128; brow0 = blockIdx.y * 128; }

    __shared__ u16 ABs[2][2][128 * 32];   // [buf][A/B][m*32 + c8'*8]

    const int tid  = threadIdx.x;
    const int w    = tid >> 6, lane = tid & 63;
    const int wr   = w >> 1, wc = w & 1;
    const int t16  = lane & 15, q4 = lane >> 4;

    const int dmr  = lane >> 2;
    const int dmc8 = (lane & 3) ^ ((lane >> 2) & 3) ^ ((lane >> 4) & 3);

    f32x4 acc[4][4];
    #pragma unroll
    for (int mt = 0; mt < 4; ++mt)
        #pragma unroll
        for (int nt = 0; nt < 4; ++nt)
            acc[mt][nt] = (f32x4){0.f, 0.f, 0.f, 0.f};

    #define QKV_DMA(p, k0)                                                      \
        _Pragma("unroll")                                                       \
        for (int i = 0; i < 2; ++i) {                                           \
            const int c = w * 2 + i;                                            \
            dma16(&Ap[(size_t)(arow0 + c * 16 + dmr) * HID + (k0) + dmc8 * 8],  \
                  &ABs[p][0][c * 512]);                                         \
            dma16(&Bp[(size_t)(brow0 + c * 16 + dmr) * HID + (k0) + dmc8 * 8],  \
                  &ABs[p][1][c * 512]);                                         \
        }

    const int swz = (t16 ^ (t16 >> 2)) & 3;

    auto qstep = [&](const int p) {
        short8 af[4], bf[4];
        #pragma unroll
        for (int mt = 0; mt < 4; ++mt)
            af[mt] = *(const short8*)&ABs[p][0][(wr * 64 + mt * 16 + t16) * 32 + (q4 ^ swz) * 8];
        #pragma unroll
        for (int nt = 0; nt < 4; ++nt)
            bf[nt] = *(const short8*)&ABs[p][1][(wc * 64 + nt * 16 + t16) * 32 + (q4 ^ swz) * 8];
        #pragma unroll
        for (int mt = 0; mt < 4; ++mt)
            #pragma unroll
            for (int nt = 0; nt < 4; ++nt)
                acc[mt][nt] = __builtin_amdgcn_mfma_f32_16x16x32_bf16(
                    af[mt], bf[nt], acc[mt][nt], 0, 0, 0);
    };

    QKV_DMA(0, 0)
    for (int it = 0; it < 16; it += 2) {
        __syncthreads();
        QKV_DMA(1, (it + 1) * 32)
        qstep(0);
        __syncthreads();
        if (it + 2 < 16) { QKV_DMA(0, (it + 2) * 32) }
        qstep(1);
    }

    if (z < 2) {
        // Q/K epilogue: strip St[token np][dim] per half-pass; coalesced stores.
        const float qs = (z == 0) ? 0.125f * LOG2E : 1.0f;
        u16* Cg = (z == 0) ? Qg : Kg;
        u16 (*St)[72] = (u16(*)[72])&ABs[0][0][0];
        #pragma unroll
        for (int p = 0; p < 2; ++p) {
            __syncthreads();
            if (wr == p) {
                #pragma unroll
                for (int mt = 0; mt < 4; ++mt) {
                    const f32x4 bv = *(const f32x4*)&bias[arow0 + p * 64 + mt * 16 + q4 * 4];
                    #pragma unroll
                    for (int nt = 0; nt < 4; ++nt) {
                        const int np = wc * 64 + nt * 16 + t16;
                        uint2 pk;
                        pk.x = pktrunc((acc[mt][nt][0] + bv[0]) * qs,
                                       (acc[mt][nt][1] + bv[1]) * qs);
                        pk.y = pktrunc((acc[mt][nt][2] + bv[2]) * qs,
                                       (acc[mt][nt][3] + bv[3]) * qs);
                        *(uint2*)&St[np][mt * 16 + q4 * 4] = pk;
                    }
                }
            }
            __syncthreads();
            const int h = blockIdx.y * 2 + p;
            #pragma unroll
            for (int it = 0; it < 4; ++it) {
                const int task = tid + it * 256;
                const int np = task >> 3, ch = task & 7;
                const int nf = brow0 + np;
                const int b = nf >> 11, n = nf & (N_ - 1);
                *(short8*)&Cg[(((size_t)(b * NH + h)) * N_ + n) * HD + ch * 8] =
                    *(const short8*)&St[np][ch * 8];
            }
        }
    } else {
        // V epilogue: frag-packed V^T (n' = 64*(n/64) + (n%16)*4 + (n%64)/16).
        u16 (*St)[72] = (u16(*)[72])&ABs[0][0][0];
        const int b = arow0 >> 11;
        #pragma unroll
        for (int p = 0; p < 2; ++p) {
            __syncthreads();
            if (wr == p) {
                #pragma unroll
                for (int nt = 0; nt < 4; ++nt) {
                    const int jp = wc * 64 + nt * 16 + t16;
                    const float bv = bias[brow0 + jp];
                    #pragma unroll
                    for (int mt = 0; mt < 4; ++mt) {
                        uint2 pk;
                        pk.x = pktrunc(acc[mt][nt][0] + bv, acc[mt][nt][1] + bv);
                        pk.y = pktrunc(acc[mt][nt][2] + bv, acc[mt][nt][3] + bv);
                        *(uint2*)&St[jp][mt * 16 + q4 * 4] = pk;
                    }
                }
            }
            __syncthreads();
            const int nb = (arow0 & (N_ - 1)) + p * 64;
            #pragma unroll
            for (int it = 0; it < 2; ++it) {
                const int task = tid + it * 256;
                const int jp = task >> 2, qc = task & 3;
                u16 v[16];
                #pragma unroll
                for (int e = 0; e < 16; ++e) {
                    const int np = qc * 16 + e;
                    const int n  = ((np & 3) << 4) | (np >> 2);
                    v[e] = St[jp][n];
                }
                const int j = brow0 + jp, h = j >> 6, d = j & 63;
                u16* dst = &Vtg[(((size_t)(b * NH + h)) * HD + d) * N_ + nb + qc * 16];
                *(short8*)(dst)     = *(const short8*)&v[0];
                *(short8*)(dst + 8) = *(const short8*)&v[8];
            }
        }
    }
}

// ---------------------------------------------------------------------------
// MFMA flash attention, K-SPLIT x2, 64 Q-rows PER WAVE (mt=4): K/V LDS reads
// amortized over 2x the MFMA work (32 b128-eq LDS ops serve 72 MFMAs per
// wave-tile). Block = 4 waves = 256 Q-rows; grid (8, 32, 2) = 512 blocks.
// Fixed-max softmax, raw v_exp_f32, mask via bitwise AND on packed P,
// row-sum via ones-MFMA. Emits un-normalized partial O (bf16) + row-sum.
// ---------------------------------------------------------------------------
__global__ __launch_bounds__(256, 2) void flash_mfma(
    const u16* __restrict__ Qg, const u16* __restrict__ Kg,
    const u16* __restrict__ Vtg, const unsigned char* __restrict__ msk,
    u16* __restrict__ Op, float* __restrict__ Lp)
{
    __shared__ u16 KVs[2][2][64 * 64];    // [buf][K/Vt][row*64 + c8'*8]  32 KB
    __shared__ u16 Ps[4][64][72];         // per-wave P strip [row][c]    36 KB
    __shared__ unsigned Mnd[16][32];      // AND-masks [kt][t16*2 + word]  2 KB

    const int tid = threadIdx.x;
    const int w = tid >> 6, lane = tid & 63;
    const int t16 = lane & 15, q4 = lane >> 4;
    const int bh = blockIdx.y, b = bh >> 3;
    const int z = blockIdx.z;
    const int kofs = z * (N_ / 2);
    const int qrow0 = blockIdx.x * 256;
    const int qbase = qrow0 + w * 64;

    const size_t hb = (size_t)bh * N_ * HD;
    const u16* Qh  = Qg + hb;
    const u16* Kh  = Kg + hb;
    const u16* Vth = Vtg + hb;
    const unsigned char* mrow = msk + b * N_;

    #pragma unroll
    for (int it = 0; it < 2; ++it) {
        const int e = tid + it * 256;
        const int kt = e >> 5, sl = e & 31;
        const int tt = sl >> 1, wd = sl & 1;
        const int k0 = kofs + kt * 64 + wd * 32 + tt;
        const unsigned lo = mrow[k0]      ? 0u : 0x0000FFFFu;
        const unsigned hi = mrow[k0 + 16] ? 0u : 0xFFFF0000u;
        Mnd[kt][sl] = lo | hi;
    }

    // Q fragments: 64 rows/wave (A-layout m = mt*16 + t16, k = q4*8 + j)
    short8 qf[4][2];
    #pragma unroll
    for (int mt = 0; mt < 4; ++mt)
        #pragma unroll
        for (int kk = 0; kk < 2; ++kk)
            qf[mt][kk] = *(const short8*)
                &Qh[(size_t)(qbase + mt * 16 + t16) * HD + kk * 32 + q4 * 8];

    const short8 ones8 = {0x3F80, 0x3F80, 0x3F80, 0x3F80,
                          0x3F80, 0x3F80, 0x3F80, 0x3F80};

    f32x4 o[4][4], ls[4];
    #pragma unroll
    for (int mt = 0; mt < 4; ++mt) {
        #pragma unroll
        for (int nt = 0; nt < 4; ++nt) o[mt][nt] = (f32x4){0.f, 0.f, 0.f, 0.f};
        ls[mt] = (f32x4){0.f, 0.f, 0.f, 0.f};
    }

    const int dmr  = lane >> 3;
    const int dmc8 = (lane & 7) ^ ((lane >> 3) & 7);

    #define FLASH_DMA(p, kb)                                                    \
        _Pragma("unroll")                                                       \
        for (int i = 0; i < 2; ++i) {                                           \
            const int c = w * 2 + i;                                            \
            dma16(&Kh[(size_t)((kb) + c * 8 + dmr) * HD + dmc8 * 8],            \
                  &KVs[p][0][c * 512]);                                         \
            dma16(&Vth[(size_t)(c * 8 + dmr) * N_ + (kb) + dmc8 * 8],           \
                  &KVs[p][1][c * 512]);                                         \
        }

    const int swz7 = t16 & 7;

    auto fstep = [&](const int p, const int kt) {
        // S = Q K^T (1/8 and log2e pre-folded into Q)
        f32x4 s[4][4];
        #pragma unroll
        for (int mt = 0; mt < 4; ++mt)
            #pragma unroll
            for (int f = 0; f < 4; ++f)
                s[mt][f] = (f32x4){0.f, 0.f, 0.f, 0.f};
        #pragma unroll
        for (int f = 0; f < 4; ++f) {
            #pragma unroll
            for (int kk = 0; kk < 2; ++kk) {
                const short8 kf = *(const short8*)
                    &KVs[p][0][(f * 16 + t16) * 64 + ((kk * 4 + q4) ^ swz7) * 8];
                #pragma unroll
                for (int mt = 0; mt < 4; ++mt)
                    s[mt][f] = __builtin_amdgcn_mfma_f32_16x16x32_bf16(
                        qf[mt][kk], kf, s[mt][f], 0, 0, 0);
            }
        }

        const uint2 mnd = *(const uint2*)&Mnd[kt][t16 * 2];

        // exp2 + truncation-pack + mask-AND + P store
        #pragma unroll
        for (int mt = 0; mt < 4; ++mt) {
            #pragma unroll
            for (int r = 0; r < 4; ++r) {
                const float e0 = __builtin_amdgcn_exp2f(s[mt][0][r]);
                const float e1 = __builtin_amdgcn_exp2f(s[mt][1][r]);
                const float e2 = __builtin_amdgcn_exp2f(s[mt][2][r]);
                const float e3 = __builtin_amdgcn_exp2f(s[mt][3][r]);
                uint2 pk;
                pk.x = pktrunc(e0, e1) & mnd.x;
                pk.y = pktrunc(e2, e3) & mnd.y;
                *(uint2*)&Ps[w][mt * 16 + q4 * 4 + r][t16 * 4] = pk;
            }
        }

        // O += P V ; row-sum += P * ones
        short8 pf[4][2];
        #pragma unroll
        for (int mt = 0; mt < 4; ++mt)
            #pragma unroll
            for (int kk = 0; kk < 2; ++kk)
                pf[mt][kk] = *(const short8*)&Ps[w][mt * 16 + t16][kk * 32 + q4 * 8];
        #pragma unroll
        for (int mt = 0; mt < 4; ++mt)
            #pragma unroll
            for (int kk = 0; kk < 2; ++kk)
                ls[mt] = __builtin_amdgcn_mfma_f32_16x16x32_bf16(
                    pf[mt][kk], ones8, ls[mt], 0, 0, 0);
        #pragma unroll
        for (int nt = 0; nt < 4; ++nt) {
            #pragma unroll
            for (int kk = 0; kk < 2; ++kk) {
                const short8 vf = *(const short8*)
                    &KVs[p][1][(nt * 16 + t16) * 64 + ((kk * 4 + q4) ^ swz7) * 8];
                #pragma unroll
                for (int mt = 0; mt < 4; ++mt)
                    o[mt][nt] = __builtin_amdgcn_mfma_f32_16x16x32_bf16(
                        pf[mt][kk], vf, o[mt][nt], 0, 0, 0);
            }
        }
    };

    FLASH_DMA(0, kofs)
    for (int kt = 0; kt < 16; kt += 2) {
        __syncthreads();
        FLASH_DMA(1, kofs + (kt + 1) * 64)
        fstep(0, kt);
        __syncthreads();
        if (kt + 2 < 16) { FLASH_DMA(0, kofs + (kt + 2) * 64) }
        fstep(1, kt + 1);
    }

    // partial epilogue: un-normalized O (bf16) + row-sum (fp32, lane t16==0)
    const size_t obase = (((size_t)z * 32 + bh)) * N_ * HD;
    #pragma unroll
    for (int mt = 0; mt < 4; ++mt) {
        #pragma unroll
        for (int r = 0; r < 4; ++r) {
            const int n = qbase + mt * 16 + q4 * 4 + r;
            if (t16 == 0) Lp[((size_t)z * 32 + bh) * N_ + n] = ls[mt][r];
            #pragma unroll
            for (int nt = 0; nt < 4; ++nt)
                Op[obase + (size_t)n * HD + nt * 16 + t16] = f2bf(o[mt][nt][r]);
        }
    }
}

// ---------------------------------------------------------------------------
// O-projection GEMM with FUSED K-split combine + per-head normalization.
// Tile 64x128, grid (128,4) = 512 blocks. A-side VALU-staged (combine +
// normalize + pack, all 256 threads); B-side (wo) DMA dbuf. One barrier/step.
// ---------------------------------------------------------------------------
__global__ __launch_bounds__(256) void gemm_o2(
    const u16* __restrict__ Op, const float* __restrict__ Lp,
    const u16* __restrict__ W, const float* __restrict__ bias,
    float* __restrict__ C)
{
    __shared__ u16 As[2][64][40];         // padded, VALU-staged
    __shared__ u16 Bs[2][128 * 32];       // DMA, XOR-swizzled

    const int tid  = threadIdx.x;
    const int row0 = blockIdx.x * 64, col0 = blockIdx.y * 128;
    const int w    = tid >> 6, lane = tid & 63;
    const int wr   = w >> 1, wc = w & 1;
    const int t16  = lane & 15, q4 = lane >> 4;

    const int dmr  = lane >> 2;
    const int dmc8 = (lane & 3) ^ ((lane >> 2) & 3) ^ ((lane >> 4) & 3);

    f32x4 acc[2][4];
    #pragma unroll
    for (int mt = 0; mt < 2; ++mt)
        #pragma unroll
        for (int nt = 0; nt < 4; ++nt) acc[mt][nt] = (f32x4){0.f, 0.f, 0.f, 0.f};

    #define O2_DMA(p, k0)                                                       \
        _Pragma("unroll")                                                       \
        for (int i = 0; i < 2; ++i) {                                           \
            const int c = w * 2 + i;                                            \
            dma16(&W[(size_t)(col0 + c * 16 + dmr) * HID + (k0) + dmc8 * 8],    \
                  &Bs[p][c * 512]);                                             \
        }

    // A prefetch state: thread handles row tr (0..63), dims dcol..dcol+7
    const int tr = tid >> 2, dcol = (tid & 3) * 8;
    const int itok = row0 + tr;
    const int ab = itok >> 11, an = itok & (N_ - 1);
    short8 a0, a1;
    float inv;
    const size_t OP_HALF = (size_t)32 * N_ * HD;

    auto aload = [&](const int t) {
        const int h = t >> 1, dk = (t & 1) * 32;
        const size_t li  = ((size_t)(ab * NH + h)) * N_ + an;
        const size_t off = li * HD + dk + dcol;
        a0 = *(const short8*)&Op[off];
        a1 = *(const short8*)&Op[off + OP_HALF];
        inv = 1.f / (Lp[li] + Lp[li + (size_t)32 * N_]);
    };

    const int swz = (t16 ^ (t16 >> 2)) & 3;

    auto ostep = [&](const int p, const int t) {
        // stage A(t): combine halves, normalize, pack
        {
            float v[8];
            #pragma unroll
            for (int i = 0; i < 8; ++i)
                v[i] = (bf2f((u16)a0[i]) + bf2f((u16)a1[i])) * inv;
            uint4 pk;
            pk.x = pktrunc(v[0], v[1]);
            pk.y = pktrunc(v[2], v[3]);
            pk.z = pktrunc(v[4], v[5]);
            pk.w = pktrunc(v[6], v[7]);
            *(uint4*)&As[p][tr][dcol] = pk;
        }
        __syncthreads();             // A(t) visible; drains B-DMA(t)
        if (t + 1 < 16) {
            O2_DMA(p ^ 1, (t + 1) * 32)
            aload(t + 1);
        }
        // compute(t)
        short8 af[2], bf[4];
        #pragma unroll
        for (int mt = 0; mt < 2; ++mt)
            af[mt] = *(const short8*)&As[p][wr * 32 + mt * 16 + t16][q4 * 8];
        #pragma unroll
        for (int nt = 0; nt < 4; ++nt)
            bf[nt] = *(const short8*)&Bs[p][(wc * 64 + nt * 16 + t16) * 32 + (q4 ^ swz) * 8];
        #pragma unroll
        for (int mt = 0; mt < 2; ++mt)
            #pragma unroll
            for (int nt = 0; nt < 4; ++nt)
                acc[mt][nt] = __builtin_amdgcn_mfma_f32_16x16x32_bf16(
                    af[mt], bf[nt], acc[mt][nt], 0, 0, 0);
    };

    O2_DMA(0, 0)
    aload(0);
    for (int t = 0; t < 16; t += 2) {
        ostep(0, t);
        ostep(1, t + 1);
    }

    // epilogue: fp32 out + bias (normalization already applied on A)
    #pragma unroll
    for (int nt = 0; nt < 4; ++nt) {
        const int j = col0 + wc * 64 + nt * 16 + t16;
        const float bv = bias[j];
        #pragma unroll
        for (int mt = 0; mt < 2; ++mt)
            #pragma unroll
            for (int r = 0; r < 4; ++r) {
                const int i = row0 + wr * 32 + mt * 16 + q4 * 4 + r;
                C[(size_t)i * HID + j] = acc[mt][nt][r] + bv;
            }
    }
}

// ---------------------------------------------------------------------------
extern "C" void kernel_launch(void* const* d_in, const int* in_sizes, int n_in,
                              void* d_out, int out_size, void* d_ws, size_t ws_size,
                              hipStream_t stream) {
    const float* x  = (const float*)d_in[0];
    // d_in[1] = cancer_type (unused: bias_emb/keymod_emb cancel in softmax)
    const unsigned char* mask = (const unsigned char*)d_in[2];
    const float* wq = (const float*)d_in[3];
    const float* bq = (const float*)d_in[4];
    const float* wk = (const float*)d_in[5];
    const float* bk = (const float*)d_in[6];
    const float* wv = (const float*)d_in[7];
    const float* bv = (const float*)d_in[8];
    const float* wo = (const float*)d_in[9];
    const float* bo = (const float*)d_in[10];

    char* ws = (char*)d_ws;
    u16* xb  = (u16*)(ws);
    u16* wqb = (u16*)(ws + (8u << 20));
    u16* wkb = (u16*)(ws + (8u << 20) + (512u << 10));
    u16* wvb = (u16*)(ws + (8u << 20) + (1024u << 10));
    u16* wob = (u16*)(ws + (8u << 20) + (1536u << 10));
    u16* Qg  = (u16*)(ws + (10u << 20));
    u16* Kg  = (u16*)(ws + (18u << 20));
    u16* Vtg = (u16*)(ws + (26u << 20));
    u16* Op  = (u16*)(ws + (34u << 20));        // 16 MB partial O (bf16)
    float* Lp = (float*)(ws + (50u << 20));     // 512 KB partial row-sums

    cvt_all<<<5120, 256, 0, stream>>>(x, wq, wk, wv, wo, xb, wqb, wkb, wvb, wob);

    gemm_qkv<<<dim3(TOK / 128, HID / 128, 3), 256, 0, stream>>>(
        xb, wqb, wkb, wvb, bq, bk, bv, Qg, Kg, Vtg);

    flash_mfma<<<dim3(N_ / 256, B_ * NH, 2), 256, 0, stream>>>(
        Qg, Kg, Vtg, mask, Op, Lp);

    gemm_o2<<<dim3(TOK / 64, HID / 128), 256, 0, stream>>>(
        Op, Lp, wob, bo, (float*)d_out);
}